// Round 8
// baseline (96.448 us; speedup 1.0000x reference)
//
#include <hip/hip_runtime.h>
#include <hip/hip_bf16.h>

// Problem: VectorQuantizer, B=8 C=16 H=64 W=64, D=1, N=512.
// E = 524288 input/output elements + 2 scalar losses.
//
// Reference semantics (including the deliberate reshape bug):
//   argmin_flat[i] over n of (x_flat[i] - weight[n])^2, i in BCHW order
//   quantized[b,c,h,w] = weight[ argmin_flat[ ((b*H+h)*W+w)*C + c ] ]
//   both losses = mean over BCHW of (x - quantized)^2
//
// R4: sorted-codebook predecessor search (9-step branchless binary search),
//     exact fp32 sub-then-square neighbor compare. absmax=0 verified.
// R6 lesson: 4096 same-address atomics serialize (~27cyc each) = +50us.
// R8: fuse reduce into main via HIERARCHICAL completion counters:
//     1024 blocks -> 32 counters (128B-padded: 32 parallel RMW chains),
//     group winners -> 1 level-2 counter, final winner block does a
//     block-wide sum of the plain-stored partials. 3 dispatches -> 2.

#define E_TOTAL 524288
#define NCODE   512
#define BLOCK   256
#define M       2
#define NBLOCKS_M (E_TOTAL / (BLOCK * M))   // 1024 blocks, 16 waves/CU
#define GROUPS  32
#define GSIZE   (NBLOCKS_M / GROUPS)        // 32

#define SKEW(a) ((a) + ((a) >> 5))          // LDS anti-conflict skew

// ws layout (bytes): sorted @0 (2048), partials @4096 (8192),
// cnt1 @16384 (32 counters, 128B stride), cnt2 @20480.

// ---- prep: rank-sort the 512 codes into ws; zero completion counters ----
__global__ __launch_bounds__(64) void vq_prep_kernel(
    const float* __restrict__ wt, float* __restrict__ sorted,
    unsigned* __restrict__ cnt1, unsigned* __restrict__ cnt2) {
  __shared__ float4 lw4[NCODE / 4];   // 2 KB
  const int t = threadIdx.x;
  lw4[t] = ((const float4*)wt)[t];
  lw4[t + 64] = ((const float4*)wt)[t + 64];
  if (blockIdx.x == 0) {              // ws is re-poisoned 0xAA every call
    if (t < GROUPS) cnt1[t * 32] = 0u;
    if (t == 32) *cnt2 = 0u;
  }
  __syncthreads();

  const int i = blockIdx.x * 64 + t;        // code index this thread ranks
  const float v = ((const float*)lw4)[i];
  int r = 0;
#pragma unroll 8
  for (int j = 0; j < NCODE / 4; ++j) {
    const float4 u = lw4[j];                // wave-uniform ds_read_b128
    const int n0 = 4 * j;
    r += (u.x < v || (u.x == v && (n0 + 0) < i)) ? 1 : 0;  // stable rank
    r += (u.y < v || (u.y == v && (n0 + 1) < i)) ? 1 : 0;  // (dup-safe)
    r += (u.z < v || (u.z == v && (n0 + 2) < i)) ? 1 : 0;
    r += (u.w < v || (u.w == v && (n0 + 3) < i)) ? 1 : 0;
  }
  sorted[r] = v;
}

// ---- main: search + outputs + partials + fused hierarchical reduce ----
__global__ __launch_bounds__(BLOCK) void vq_main_kernel(
    const float* __restrict__ x, const float* __restrict__ sorted,
    float* __restrict__ out, double* __restrict__ partial,
    unsigned* __restrict__ cnt1, unsigned* __restrict__ cnt2) {
  __shared__ float ls[SKEW(NCODE + 1) + 1];  // skewed; logical 0..512
  __shared__ double lsum[BLOCK / 64];
  __shared__ int winner;

  const int t = threadIdx.x;
  const int tid = blockIdx.x * BLOCK + t;
  const int o0 = tid * M;               // two consecutive outputs, BCHW flat
  // Decode o0 -> (b,c,h,w): W=64 (6b), H=64 (6b), C=16 (4b), B=8 (3b).
  // o0 even => w even => o1=o0+1 shares b,c,h; ip1 = ip0 + 16.
  const int w = o0 & 63;
  const int h = (o0 >> 6) & 63;
  const int c = (o0 >> 12) & 15;
  const int b = o0 >> 16;
  // Scrambled source index (the reference's reshape-as-[B,H,W,C] bug):
  const int ip0 = b * 65536 + h * 1024 + w * 16 + c;

  // Issue gathers + coalesced loss-load early; latency overlaps staging.
  const float g0 = x[ip0];
  const float g1 = x[ip0 + 16];
  const float2 xo = ((const float2*)x)[tid];

  // Stage sorted codebook, skewed: logical a -> physical a+(a>>5).
  for (int k = t; k < NCODE; k += BLOCK) ls[SKEW(k + 1)] = sorted[k];
  if (t == 0) ls[SKEW(0)] = -3.0e38f;   // left sentinel (logical 0)
  __syncthreads();

  // Branchless lower-bound over 512: idx = min(#{sorted <= x}, 511).
  unsigned i0 = 0, i1 = 0;
#pragma unroll
  for (unsigned step = NCODE / 2; step; step >>= 1) {
    const float s0 = ls[SKEW(i0 + step)];
    const float s1 = ls[SKEW(i1 + step)];
    i0 = (s0 <= g0) ? i0 + step : i0;   // predicated (v_cndmask)
    i1 = (s1 <= g1) ? i1 + step : i1;
  }
  const float l0 = ls[SKEW(i0)], r0 = ls[SKEW(i0 + 1)];
  const float l1 = ls[SKEW(i1)], r1 = ls[SKEW(i1 + 1)];
  // Exact reference arithmetic: fp32 subtract then square.
  const float dl0 = g0 - l0, dr0 = g0 - r0;
  const float dl1 = g1 - l1, dr1 = g1 - r1;
  const float wq0 = (dl0 * dl0 <= dr0 * dr0) ? l0 : r0;
  const float wq1 = (dl1 * dl1 <= dr1 * dr1) ? l1 : r1;

  ((float2*)out)[tid] = make_float2(wq0, wq1);

  const float d0 = xo.x - wq0;
  const float d1 = xo.y - wq1;
  double ds = (double)d0 * (double)d0 + (double)d1 * (double)d1;

  // Wave(64) shuffle reduction, then per-block partial (plain store).
#pragma unroll
  for (int off = 32; off > 0; off >>= 1) ds += __shfl_down(ds, off, 64);
  const int lane = t & 63, wave = t >> 6;
  if (lane == 0) lsum[wave] = ds;
  __syncthreads();
  if (t == 0) {
    double s = 0.0;
#pragma unroll
    for (int i = 0; i < BLOCK / 64; ++i) s += lsum[i];
    partial[blockIdx.x] = s;
    __threadfence();                    // release partial before counting
    winner = 0;
    const unsigned old = atomicAdd(&cnt1[(blockIdx.x >> 5) * 32], 1u);
    if (old == GSIZE - 1) {             // group complete
      __threadfence();
      const unsigned old2 = atomicAdd(cnt2, 1u);
      if (old2 == GROUPS - 1) winner = 1;  // all groups complete
    }
  }
  __syncthreads();
  if (winner) {                         // one block, block-wide final sum
    __threadfence();                    // acquire: partials now visible
    double s2 = 0.0;
    for (int k = t; k < NBLOCKS_M; k += BLOCK) s2 += partial[k];
#pragma unroll
    for (int off = 32; off > 0; off >>= 1) s2 += __shfl_down(s2, off, 64);
    if (lane == 0) lsum[wave] = s2;
    __syncthreads();
    if (t == 0) {
      double tot = 0.0;
#pragma unroll
      for (int i = 0; i < BLOCK / 64; ++i) tot += lsum[i];
      const float m = (float)(tot / (double)E_TOTAL);
      out[E_TOTAL] = m;      // q_latent_loss
      out[E_TOTAL + 1] = m;  // e_latent_loss (identical forward value)
    }
  }
}

extern "C" void kernel_launch(void* const* d_in, const int* in_sizes, int n_in,
                              void* d_out, int out_size, void* d_ws, size_t ws_size,
                              hipStream_t stream) {
  const float* x = (const float*)d_in[0];    // 524288 fp32, BCHW flat
  const float* wt = (const float*)d_in[1];   // 512 fp32 (D=1 row)
  float* out = (float*)d_out;                // 524290 fp32
  float* sorted = (float*)d_ws;              // 512 fp32
  double* partial = (double*)((char*)d_ws + 4096);    // 1024 doubles
  unsigned* cnt1 = (unsigned*)((char*)d_ws + 16384);  // 32 @ 128B stride
  unsigned* cnt2 = (unsigned*)((char*)d_ws + 20480);

  vq_prep_kernel<<<8, 64, 0, stream>>>(wt, sorted, cnt1, cnt2);
  vq_main_kernel<<<NBLOCKS_M, BLOCK, 0, stream>>>(x, sorted, out, partial,
                                                  cnt1, cnt2);
}

// Round 9
// 77.524 us; speedup vs baseline: 1.2441x; 1.2441x over previous
//
#include <hip/hip_runtime.h>
#include <hip/hip_bf16.h>

// Problem: VectorQuantizer, B=8 C=16 H=64 W=64, D=1, N=512.
// E = 524288 input/output elements + 2 scalar losses.
//
// Reference semantics (including the deliberate reshape bug):
//   argmin_flat[i] over n of (x_flat[i] - weight[n])^2, i in BCHW order
//   quantized[b,c,h,w] = weight[ argmin_flat[ ((b*H+h)*W+w)*C + c ] ]
//   both losses = mean over BCHW of (x - quantized)^2
//
// R4: sorted-codebook predecessor search, exact fp32 sub-then-square
//     neighbor compare. absmax=0 verified.
// R6 lesson: 2048+ same-address device atomics serialize -> +45us.
// R8 lesson: per-block __threadfence (device scope, cross-XCD L2
//     writeback) costs ~17us across 1024 blocks — any cross-workgroup
//     completion protocol loses more than the one saved graph node.
// R9: revert to the measured-best R7 structure (79.2 us): 3 dispatches,
//     plain-store per-block partials, no device fences, no atomics.

#define E_TOTAL 524288
#define NCODE   512
#define BLOCK   256
#define M       2
#define NBLOCKS_M (E_TOTAL / (BLOCK * M))   // 1024 blocks, 16 waves/CU

#define SKEW(a) ((a) + ((a) >> 5))          // LDS anti-conflict skew

// ---- prep: rank-sort the 512 codes ascending into ws ----
__global__ __launch_bounds__(64) void vq_prep_kernel(
    const float* __restrict__ wt, float* __restrict__ sorted) {
  __shared__ float4 lw4[NCODE / 4];   // 2 KB
  const int t = threadIdx.x;
  lw4[t] = ((const float4*)wt)[t];
  lw4[t + 64] = ((const float4*)wt)[t + 64];
  __syncthreads();

  const int i = blockIdx.x * 64 + t;        // code index this thread ranks
  const float v = ((const float*)lw4)[i];
  int r = 0;
#pragma unroll 8
  for (int j = 0; j < NCODE / 4; ++j) {
    const float4 u = lw4[j];                // wave-uniform ds_read_b128
    const int n0 = 4 * j;
    r += (u.x < v || (u.x == v && (n0 + 0) < i)) ? 1 : 0;  // stable rank
    r += (u.y < v || (u.y == v && (n0 + 1) < i)) ? 1 : 0;  // (dup-safe)
    r += (u.z < v || (u.z == v && (n0 + 2) < i)) ? 1 : 0;
    r += (u.w < v || (u.w == v && (n0 + 3) < i)) ? 1 : 0;
  }
  sorted[r] = v;
}

// ---- main: binary search + neighbor compare + loss partials ----
__global__ __launch_bounds__(BLOCK) void vq_main_kernel(
    const float* __restrict__ x, const float* __restrict__ sorted,
    float* __restrict__ out, double* __restrict__ partial) {
  __shared__ float ls[SKEW(NCODE + 1) + 1];  // skewed; logical 0..512
  __shared__ double lsum[BLOCK / 64];

  const int t = threadIdx.x;
  const int tid = blockIdx.x * BLOCK + t;
  const int o0 = tid * M;               // two consecutive outputs, BCHW flat
  // Decode o0 -> (b,c,h,w): W=64 (6b), H=64 (6b), C=16 (4b), B=8 (3b).
  // o0 even => w even => o1=o0+1 shares b,c,h; ip1 = ip0 + 16.
  const int w = o0 & 63;
  const int h = (o0 >> 6) & 63;
  const int c = (o0 >> 12) & 15;
  const int b = o0 >> 16;
  // Scrambled source index (the reference's reshape-as-[B,H,W,C] bug):
  const int ip0 = b * 65536 + h * 1024 + w * 16 + c;

  // Issue gathers + coalesced loss-load early; latency overlaps staging.
  const float g0 = x[ip0];
  const float g1 = x[ip0 + 16];
  const float2 xo = ((const float2*)x)[tid];

  // Stage sorted codebook, skewed: logical a -> physical a+(a>>5).
  for (int k = t; k < NCODE; k += BLOCK) ls[SKEW(k + 1)] = sorted[k];
  if (t == 0) ls[SKEW(0)] = -3.0e38f;   // left sentinel (logical 0)
  __syncthreads();

  // Branchless lower-bound over 512: idx = min(#{sorted <= x}, 511).
  unsigned i0 = 0, i1 = 0;
#pragma unroll
  for (unsigned step = NCODE / 2; step; step >>= 1) {
    const float s0 = ls[SKEW(i0 + step)];
    const float s1 = ls[SKEW(i1 + step)];
    i0 = (s0 <= g0) ? i0 + step : i0;   // predicated (v_cndmask)
    i1 = (s1 <= g1) ? i1 + step : i1;
  }
  const float l0 = ls[SKEW(i0)], r0 = ls[SKEW(i0 + 1)];
  const float l1 = ls[SKEW(i1)], r1 = ls[SKEW(i1 + 1)];
  // Exact reference arithmetic: fp32 subtract then square.
  const float dl0 = g0 - l0, dr0 = g0 - r0;
  const float dl1 = g1 - l1, dr1 = g1 - r1;
  const float wq0 = (dl0 * dl0 <= dr0 * dr0) ? l0 : r0;
  const float wq1 = (dl1 * dl1 <= dr1 * dr1) ? l1 : r1;

  ((float2*)out)[tid] = make_float2(wq0, wq1);

  const float d0 = xo.x - wq0;
  const float d1 = xo.y - wq1;
  double ds = (double)d0 * (double)d0 + (double)d1 * (double)d1;

  // Wave(64) shuffle reduction, then per-block partial (plain store).
#pragma unroll
  for (int off = 32; off > 0; off >>= 1) ds += __shfl_down(ds, off, 64);
  const int lane = t & 63, wave = t >> 6;
  if (lane == 0) lsum[wave] = ds;
  __syncthreads();
  if (t == 0) {
    double s = 0.0;
#pragma unroll
    for (int i = 0; i < BLOCK / 64; ++i) s += lsum[i];
    partial[blockIdx.x] = s;  // full overwrite: no ws zeroing needed
  }
}

__global__ __launch_bounds__(BLOCK) void vq_reduce_kernel(
    const double* __restrict__ partial, float* __restrict__ out) {
  __shared__ double lsum[BLOCK / 64];
  const int t = threadIdx.x;
  double s = 0.0;
  for (int k = t; k < NBLOCKS_M; k += BLOCK) s += partial[k];
#pragma unroll
  for (int off = 32; off > 0; off >>= 1) s += __shfl_down(s, off, 64);
  const int lane = t & 63, wave = t >> 6;
  if (lane == 0) lsum[wave] = s;
  __syncthreads();
  if (t == 0) {
    double tot = 0.0;
#pragma unroll
    for (int i = 0; i < BLOCK / 64; ++i) tot += lsum[i];
    const float m = (float)(tot / (double)E_TOTAL);
    out[E_TOTAL] = m;      // q_latent_loss
    out[E_TOTAL + 1] = m;  // e_latent_loss (identical forward value)
  }
}

extern "C" void kernel_launch(void* const* d_in, const int* in_sizes, int n_in,
                              void* d_out, int out_size, void* d_ws, size_t ws_size,
                              hipStream_t stream) {
  const float* x = (const float*)d_in[0];    // 524288 fp32, BCHW flat
  const float* wt = (const float*)d_in[1];   // 512 fp32 (D=1 row)
  float* out = (float*)d_out;                // 524290 fp32
  float* sorted = (float*)d_ws;              // 512 fp32 (2048 B)
  double* partial = (double*)((char*)d_ws + 4096);  // 1024 doubles

  vq_prep_kernel<<<8, 64, 0, stream>>>(wt, sorted);
  vq_main_kernel<<<NBLOCKS_M, BLOCK, 0, stream>>>(x, sorted, out, partial);
  vq_reduce_kernel<<<1, BLOCK, 0, stream>>>(partial, out);
}